// Round 6
// baseline (198.777 us; speedup 1.0000x reference)
//
#include <hip/hip_runtime.h>

// TrajectoryScore v5b: round-3 structure + NON-TEMPORAL global loads.
// (v5 failed to compile: __builtin_nontemporal_load needs a native vector
// pointer, not HIP_vector_type. Using clang ext_vector_type float4.)
// Theory unchanged: suspected per-XCD L2 line-allocate cap (~128 B/cy/XCD
// = 2.46 TB/s chip, matching the observed 2.4 TB/s plateau across four
// disjoint load paths, incl. LLC-resident replays). nt = "no allocate".

constexpr int ELT_BATCH      = 64;
constexpr int OBS_PER_ELT    = 100000;
constexpr int F4_PER_SEG     = OBS_PER_ELT * 3 / 4;          // 75000
constexpr int BLOCK          = 256;
constexpr int BLOCKS_PER_SEG = 100;
constexpr int F4_PER_BLOCK   = F4_PER_SEG / BLOCKS_PER_SEG;  // 750 f4 = 3000 floats
constexpr int OBS_PER_BLOCK  = OBS_PER_ELT / BLOCKS_PER_SEG; // 1000 obs

typedef float vfloat4 __attribute__((ext_vector_type(4)));

__device__ __forceinline__ float wave_reduce_sum(float v) {
    #pragma unroll
    for (int off = 32; off > 0; off >>= 1)
        v += __shfl_down(v, off, 64);
    return v;
}

__global__ __launch_bounds__(BLOCK) void TrajectoryScore_58145267253396_kernel(
    const vfloat4* __restrict__ pred4,
    const vfloat4* __restrict__ obs4,
    const float*   __restrict__ h_arr,
    const float*   __restrict__ lam_arr,
    const float*   __restrict__ th_arr,
    float*         __restrict__ out)
{
    __shared__ float q2[F4_PER_BLOCK * 4];   // 3000 floats = 12 KB (squared diffs)

    const int seg     = blockIdx.x / BLOCKS_PER_SEG;
    const int blk     = blockIdx.x % BLOCKS_PER_SEG;
    const int tid     = threadIdx.x;
    const int f4_base = seg * F4_PER_SEG + blk * F4_PER_BLOCK;

    // --- Stage 1: issue all global loads (unit-stride dwordx4, nt flag) ---
    vfloat4 a[3], b[3];
    #pragma unroll
    for (int k = 0; k < 3; ++k) {
        const int idx = tid + k * BLOCK;          // k=0,1 always < 750; k=2 predicated
        if (idx < F4_PER_BLOCK) {
            a[k] = __builtin_nontemporal_load(&pred4[f4_base + idx]);
            b[k] = __builtin_nontemporal_load(&obs4[f4_base + idx]);
        }
    }

    // Per-segment params (overlaps the loads' latency).
    const float h    = h_arr[seg];
    const float lam  = lam_arr[seg];
    const float th   = th_arr[seg];
    const float coef = h * lam / (1.0f - __expf(-lam));
    const float omh  = 1.0f - h;
    const float nli  = -lam / th;

    // --- Stage 2: elementwise squared diff -> LDS ---
    #pragma unroll
    for (int k = 0; k < 3; ++k) {
        const int idx = tid + k * BLOCK;
        if (idx < F4_PER_BLOCK) {
            const vfloat4 d = a[k] - b[k];
            const vfloat4 s = d * d;
            reinterpret_cast<vfloat4*>(q2)[idx] = s;
        }
    }
    __syncthreads();

    // --- Stage 3: regroup 3 floats/obs from LDS, score, accumulate ---
    float ll = 0.0f;
    float hs = 0.0f;
    #pragma unroll
    for (int k = 0; k < 4; ++k) {
        const int t = tid + k * BLOCK;            // k=0..2 always < 1000; k=3 predicated
        if (t < OBS_PER_BLOCK) {
            const float s2    = q2[3 * t] + q2[3 * t + 1] + q2[3 * t + 2];
            const float e     = __expf(nli * s2);
            const float p_hit = coef * e;
            const float p     = p_hit + omh;
            const bool  close = s2 < th;
            const float lp    = __logf(p);
            ll += close ? lp : 0.0f;
            const float post  = p_hit / p;
            hs += (close && post > 0.95f) ? post : 0.0f;
        }
    }

    // --- Block reduction + per-segment atomics ---
    ll = wave_reduce_sum(ll);
    hs = wave_reduce_sum(hs);

    __shared__ float sll[BLOCK / 64];
    __shared__ float shs[BLOCK / 64];
    const int wave = tid >> 6;
    const int lane = tid & 63;
    if (lane == 0) { sll[wave] = ll; shs[wave] = hs; }
    __syncthreads();
    if (tid == 0) {
        float L = 0.0f, H = 0.0f;
        #pragma unroll
        for (int w = 0; w < BLOCK / 64; ++w) { L += sll[w]; H += shs[w]; }
        atomicAdd(&out[seg], L);
        atomicAdd(&out[ELT_BATCH + seg], H);
        atomicAdd(&out[2 * ELT_BATCH + seg], H);  // hits_raw == hits
    }
}

extern "C" void kernel_launch(void* const* d_in, const int* in_sizes, int n_in,
                              void* d_out, int out_size, void* d_ws, size_t ws_size,
                              hipStream_t stream) {
    const vfloat4* pred4   = (const vfloat4*)d_in[0];
    const vfloat4* obs4    = (const vfloat4*)d_in[1];
    const float*   h_arr   = (const float*)d_in[2];
    const float*   lam_arr = (const float*)d_in[3];
    const float*   th_arr  = (const float*)d_in[4];
    float* out = (float*)d_out;

    // Harness poisons d_out to 0xAA before timed replays — zero it ourselves.
    (void)hipMemsetAsync(out, 0, out_size * sizeof(float), stream);

    dim3 grid(ELT_BATCH * BLOCKS_PER_SEG);   // 6400 blocks
    dim3 block(BLOCK);
    TrajectoryScore_58145267253396_kernel<<<grid, block, 0, stream>>>(
        pred4, obs4, h_arr, lam_arr, th_arr, out);
}